// Round 1
// baseline (92.497 us; speedup 1.0000x reference)
//
#include <hip/hip_runtime.h>
#include <stdint.h>

#define B_ 64
#define K_ 8192
#define O_ 8192
#define R_ 64
#define NT 16
#define BK 128
#define NSTEP (K_ / BK)  // 64

typedef __attribute__((ext_vector_type(8))) short s16x8;   // 8 bf16 (4 VGPRs)
typedef __attribute__((ext_vector_type(4))) float f32x4;

// round-to-nearest-even f32 -> bf16, packed pair
__device__ __forceinline__ uint32_t rne_pack(float a, float b) {
  uint32_t ua = __float_as_uint(a), ub = __float_as_uint(b);
  ua += 0x7fffu + ((ua >> 16) & 1u);
  ub += 0x7fffu + ((ub >> 16) & 1u);
  return (ua >> 16) | (ub & 0xffff0000u);
}

// (w - 128) is an integer in [-128,127]: EXACT in bf16, truncation suffices
__device__ __forceinline__ uint32_t wpack(int w0, int w1) {
  float f0 = (float)(w0 - 128);
  float f1 = (float)(w1 - 128);
  return (__float_as_uint(f0) >> 16) | (__float_as_uint(f1) & 0xffff0000u);
}

// ---------------------------------------------------------------------------
// k_prep: (a) convert x (fp32 [64][8192]) -> bf16 xbg in ws (all 256 blocks)
//         (b) blocks 0..63: partial mid = x @ lora_A^T over a 128-wide K slab,
//             accumulated into ws via fp32 atomicAdd (mid zeroed by memset).
// ---------------------------------------------------------------------------
__global__ __launch_bounds__(256) void k_prep(
    const float* __restrict__ x, const float* __restrict__ lora_A,
    uint16_t* __restrict__ xbg, float* __restrict__ mid) {
  const int t = threadIdx.x;
  const int blk = blockIdx.x;

  {  // x -> bf16, 2048 elems per block, 8 per thread
    const size_t base = (size_t)blk * 2048 + (size_t)t * 8;
    float4 v0 = *(const float4*)(x + base);
    float4 v1 = *(const float4*)(x + base + 4);
    uint4 p;
    p.x = rne_pack(v0.x, v0.y);
    p.y = rne_pack(v0.z, v0.w);
    p.z = rne_pack(v1.x, v1.y);
    p.w = rne_pack(v1.z, v1.w);
    *(uint4*)(xbg + base) = p;
  }

  if (blk >= 64) return;

  __shared__ float xs[64][133];   // 133 stride: bank-spread for column reads
  __shared__ float as_[64][133];
  const int kr0 = blk * BK;
  const int row = t >> 2, seg = t & 3;
#pragma unroll
  for (int j = 0; j < 8; ++j) {
    const int c = seg * 32 + j * 4;
    float4 vx = *(const float4*)(x + (size_t)row * K_ + kr0 + c);
    float4 va = *(const float4*)(lora_A + (size_t)row * K_ + kr0 + c);
    xs[row][c] = vx.x; xs[row][c + 1] = vx.y; xs[row][c + 2] = vx.z; xs[row][c + 3] = vx.w;
    as_[row][c] = va.x; as_[row][c + 1] = va.y; as_[row][c + 2] = va.z; as_[row][c + 3] = va.w;
  }
  __syncthreads();

  const int bg = t >> 4, rg = t & 15;
  const int b0 = bg * 4, r0 = rg * 4;
  float acc[4][4];
#pragma unroll
  for (int i = 0; i < 4; ++i)
#pragma unroll
    for (int j = 0; j < 4; ++j) acc[i][j] = 0.f;

  for (int k = 0; k < BK; ++k) {
    float xv[4], av[4];
#pragma unroll
    for (int i = 0; i < 4; ++i) xv[i] = xs[b0 + i][k];
#pragma unroll
    for (int j = 0; j < 4; ++j) av[j] = as_[r0 + j][k];
#pragma unroll
    for (int i = 0; i < 4; ++i)
#pragma unroll
      for (int j = 0; j < 4; ++j) acc[i][j] += xv[i] * av[j];
  }

#pragma unroll
  for (int i = 0; i < 4; ++i)
#pragma unroll
    for (int j = 0; j < 4; ++j)
      atomicAdd(&mid[(b0 + i) * R_ + (r0 + j)], acc[i][j]);
}

// ---------------------------------------------------------------------------
// k_main: 512 blocks x 16 output channels. M=64 (batch) x NT=16, K tiled by
// 128, reg-staged double-buffered LDS, bf16 MFMA 16x16x32. LoRA folded in as
// 2 extra MFMAs (K=64) from bf16-staged mid / lora_B tiles.
// ---------------------------------------------------------------------------
__global__ __launch_bounds__(256, 2) void k_main(
    const int* __restrict__ Wq, const float* __restrict__ scale,
    const float* __restrict__ lora_B, const float* __restrict__ bias,
    const uint16_t* __restrict__ xbg, const float* __restrict__ mid,
    float* __restrict__ out) {
  __shared__ uint16_t xa[2][64][136];   // x tile   [64][128] bf16, stride 136
  __shared__ uint16_t wbs[2][NT][136];  // W tile   [16][128] bf16
  __shared__ uint16_t midb[64][72];     // mid bf16 [64][64]
  __shared__ uint16_t lob[NT][72];      // lora_B bf16 [16][64]

  const int t = threadIdx.x;
  const int o0 = blockIdx.x * NT;
  const int wave = t >> 6;
  const int lane = t & 63;
  const int il = lane & 15;
  const int g = lane >> 4;
  const int m0 = wave * 16;

  // ---- prologue: stage midb (all threads) + lob (threads 0..63) ----
  {
    const int row = t >> 2;
    const int r0 = (t & 3) * 16;
    const float* mp = mid + row * R_ + r0;
    float4 a0 = *(const float4*)(mp);
    float4 a1 = *(const float4*)(mp + 4);
    float4 a2 = *(const float4*)(mp + 8);
    float4 a3 = *(const float4*)(mp + 12);
    uint4 p0, p1;
    p0.x = rne_pack(a0.x, a0.y); p0.y = rne_pack(a0.z, a0.w);
    p0.z = rne_pack(a1.x, a1.y); p0.w = rne_pack(a1.z, a1.w);
    p1.x = rne_pack(a2.x, a2.y); p1.y = rne_pack(a2.z, a2.w);
    p1.z = rne_pack(a3.x, a3.y); p1.w = rne_pack(a3.z, a3.w);
    *(uint4*)&midb[row][r0] = p0;
    *(uint4*)&midb[row][r0 + 8] = p1;
    if (t < 64) {
      const int row2 = t >> 2;
      const float* lp = lora_B + (size_t)(o0 + row2) * R_ + r0;
      float4 c0 = *(const float4*)(lp);
      float4 c1 = *(const float4*)(lp + 4);
      float4 c2 = *(const float4*)(lp + 8);
      float4 c3 = *(const float4*)(lp + 12);
      uint4 q0, q1;
      q0.x = rne_pack(c0.x, c0.y); q0.y = rne_pack(c0.z, c0.w);
      q0.z = rne_pack(c1.x, c1.y); q0.w = rne_pack(c1.z, c1.w);
      q1.x = rne_pack(c2.x, c2.y); q1.y = rne_pack(c2.z, c2.w);
      q1.z = rne_pack(c3.x, c3.y); q1.w = rne_pack(c3.z, c3.w);
      *(uint4*)&lob[row2][r0] = q0;
      *(uint4*)&lob[row2][r0 + 8] = q1;
    }
  }

  // ---- staging coordinates ----
  const int xrow = t >> 2, xseg = t & 3;   // x: 64 rows x 4 segs of 32 elems
  const int wrow = t >> 4, wseg = t & 15;  // W: 16 rows x 16 segs of 8 ints
  const uint16_t* xsrc = xbg + (size_t)xrow * K_;
  const int* wsrc = Wq + (size_t)(o0 + wrow) * K_;

  uint4 rx0, rx1, rx2, rx3;
  int4 rw0, rw1;
#define LOADT(TT)                                         \
  do {                                                    \
    const int kt = (TT)*BK;                               \
    rx0 = *(const uint4*)(xsrc + kt + xseg * 32);         \
    rx1 = *(const uint4*)(xsrc + kt + xseg * 32 + 8);     \
    rx2 = *(const uint4*)(xsrc + kt + xseg * 32 + 16);    \
    rx3 = *(const uint4*)(xsrc + kt + xseg * 32 + 24);    \
    rw0 = *(const int4*)(wsrc + kt + wseg * 8);           \
    rw1 = *(const int4*)(wsrc + kt + wseg * 8 + 4);       \
  } while (0)

  LOADT(0);

  const float sc = scale[o0 + il];
  const float bi = bias[o0 + il];

  __syncthreads();  // midb/lob staged

  // ---- LoRA MFMAs: acc2 = mid[64x64] @ lora_B^T[64x16] ----
  f32x4 acc2 = {0.f, 0.f, 0.f, 0.f};
#pragma unroll
  for (int kf = 0; kf < 2; ++kf) {
    s16x8 am = *(const s16x8*)&midb[m0 + il][kf * 32 + g * 8];
    s16x8 bl = *(const s16x8*)&lob[il][kf * 32 + g * 8];
    acc2 = __builtin_amdgcn_mfma_f32_16x16x32_bf16(am, bl, acc2, 0, 0, 0);
  }

  // ---- main K loop ----
  f32x4 acc = {0.f, 0.f, 0.f, 0.f};
  int cur = 0;
  for (int tt = 0; tt < NSTEP; ++tt) {
    // write regs (tile tt) -> LDS[cur]
    *(uint4*)&xa[cur][xrow][xseg * 32] = rx0;
    *(uint4*)&xa[cur][xrow][xseg * 32 + 8] = rx1;
    *(uint4*)&xa[cur][xrow][xseg * 32 + 16] = rx2;
    *(uint4*)&xa[cur][xrow][xseg * 32 + 24] = rx3;
    uint4 wv;
    wv.x = wpack(rw0.x, rw0.y);
    wv.y = wpack(rw0.z, rw0.w);
    wv.z = wpack(rw1.x, rw1.y);
    wv.w = wpack(rw1.z, rw1.w);
    *(uint4*)&wbs[cur][wrow][wseg * 8] = wv;
    __syncthreads();
    if (tt + 1 < NSTEP) LOADT(tt + 1);  // prefetch overlaps compute below
#pragma unroll
    for (int kf = 0; kf < 4; ++kf) {
      s16x8 af = *(const s16x8*)&xa[cur][m0 + il][kf * 32 + g * 8];
      s16x8 bf = *(const s16x8*)&wbs[cur][il][kf * 32 + g * 8];
      acc = __builtin_amdgcn_mfma_f32_16x16x32_bf16(af, bf, acc, 0, 0, 0);
    }
    cur ^= 1;
  }
#undef LOADT

  // ---- epilogue: C/D layout col=lane&15, row=(lane>>4)*4+reg ----
#pragma unroll
  for (int j = 0; j < 4; ++j) {
    const int b = m0 + g * 4 + j;
    out[(size_t)b * O_ + o0 + il] = sc * acc[j] + bi + 0.25f * acc2[j];
  }
}

// ---------------------------------------------------------------------------
extern "C" void kernel_launch(void* const* d_in, const int* in_sizes, int n_in,
                              void* d_out, int out_size, void* d_ws, size_t ws_size,
                              hipStream_t stream) {
  const float* x = (const float*)d_in[0];
  const int* Wq = (const int*)d_in[1];
  const float* scale = (const float*)d_in[2];
  const float* lora_A = (const float*)d_in[3];
  const float* lora_B = (const float*)d_in[4];
  const float* bias = (const float*)d_in[5];
  float* out = (float*)d_out;

  uint16_t* xbg = (uint16_t*)d_ws;                              // 1 MiB bf16 x
  float* mid = (float*)((char*)d_ws + (size_t)B_ * K_ * 2);     // 16 KiB fp32

  hipMemsetAsync(mid, 0, B_ * R_ * sizeof(float), stream);
  k_prep<<<256, 256, 0, stream>>>(x, lora_A, xbg, mid);
  k_main<<<O_ / NT, 256, 0, stream>>>(Wq, scale, lora_B, bias, xbg, mid, out);
}

// Round 2
// 88.747 us; speedup vs baseline: 1.0423x; 1.0423x over previous
//
#include <hip/hip_runtime.h>
#include <stdint.h>

#define B_ 64
#define K_ 8192
#define O_ 8192
#define R_ 64
#define NT 16
#define BK 128
#define NSTEP (K_ / BK)  // 64

typedef __attribute__((ext_vector_type(8))) short s16x8;   // 8 bf16 (4 VGPRs)
typedef __attribute__((ext_vector_type(4))) float f32x4;

// round-to-nearest-even f32 -> bf16, packed pair
__device__ __forceinline__ uint32_t rne_pack(float a, float b) {
  uint32_t ua = __float_as_uint(a), ub = __float_as_uint(b);
  ua += 0x7fffu + ((ua >> 16) & 1u);
  ub += 0x7fffu + ((ub >> 16) & 1u);
  return (ua >> 16) | (ub & 0xffff0000u);
}

// (w - 128) is an integer in [-128,127]: EXACT in bf16, truncation suffices
__device__ __forceinline__ uint32_t wpack(int w0, int w1) {
  float f0 = (float)(w0 - 128);
  float f1 = (float)(w1 - 128);
  return (__float_as_uint(f0) >> 16) | (__float_as_uint(f1) & 0xffff0000u);
}

// ---------------------------------------------------------------------------
// k_prep: (a) x (fp32) -> bf16 xbg (all 256 blocks)
//         (b) blocks 0..63: partial mid = x @ lora_A^T over a 128-wide K slab,
//             accumulated via fp32 atomicAdd (mid zeroed by memset).
// ---------------------------------------------------------------------------
__global__ __launch_bounds__(256) void k_prep(
    const float* __restrict__ x, const float* __restrict__ lora_A,
    uint16_t* __restrict__ xbg, float* __restrict__ mid) {
  const int t = threadIdx.x;
  const int blk = blockIdx.x;

  {  // x -> bf16, 2048 elems per block, 8 per thread
    const size_t base = (size_t)blk * 2048 + (size_t)t * 8;
    float4 v0 = *(const float4*)(x + base);
    float4 v1 = *(const float4*)(x + base + 4);
    uint4 p;
    p.x = rne_pack(v0.x, v0.y);
    p.y = rne_pack(v0.z, v0.w);
    p.z = rne_pack(v1.x, v1.y);
    p.w = rne_pack(v1.z, v1.w);
    *(uint4*)(xbg + base) = p;
  }

  if (blk >= 64) return;

  __shared__ float xs[64][133];
  __shared__ float as_[64][133];
  const int kr0 = blk * BK;
  const int row = t >> 2, seg = t & 3;
#pragma unroll
  for (int j = 0; j < 8; ++j) {
    const int c = seg * 32 + j * 4;
    float4 vx = *(const float4*)(x + (size_t)row * K_ + kr0 + c);
    float4 va = *(const float4*)(lora_A + (size_t)row * K_ + kr0 + c);
    xs[row][c] = vx.x; xs[row][c + 1] = vx.y; xs[row][c + 2] = vx.z; xs[row][c + 3] = vx.w;
    as_[row][c] = va.x; as_[row][c + 1] = va.y; as_[row][c + 2] = va.z; as_[row][c + 3] = va.w;
  }
  __syncthreads();

  const int bg = t >> 4, rg = t & 15;
  const int b0 = bg * 4, r0 = rg * 4;
  float acc[4][4];
#pragma unroll
  for (int i = 0; i < 4; ++i)
#pragma unroll
    for (int j = 0; j < 4; ++j) acc[i][j] = 0.f;

  for (int k = 0; k < BK; ++k) {
    float xv[4], av[4];
#pragma unroll
    for (int i = 0; i < 4; ++i) xv[i] = xs[b0 + i][k];
#pragma unroll
    for (int j = 0; j < 4; ++j) av[j] = as_[r0 + j][k];
#pragma unroll
    for (int i = 0; i < 4; ++i)
#pragma unroll
      for (int j = 0; j < 4; ++j) acc[i][j] += xv[i] * av[j];
  }

#pragma unroll
  for (int i = 0; i < 4; ++i)
#pragma unroll
    for (int j = 0; j < 4; ++j)
      atomicAdd(&mid[(b0 + i) * R_ + (r0 + j)], acc[i][j]);
}

// ---------------------------------------------------------------------------
// k_main: 512 blocks x NT=16 output channels, M=64, K tiled by 128.
// 2-deep register-staged pipeline -> double-buffered LDS -> bf16 MFMA.
// LoRA folded in as 2 extra MFMAs in the prologue (buffers union'd into xa[0]).
// ---------------------------------------------------------------------------
__global__ __launch_bounds__(256, 2) void k_main(
    const int* __restrict__ Wq, const float* __restrict__ scale,
    const float* __restrict__ lora_B, const float* __restrict__ bias,
    const uint16_t* __restrict__ xbg, const float* __restrict__ mid,
    float* __restrict__ out) {
  __shared__ uint16_t xa[2][64][136];   // x tile  [64][128] bf16, stride 136
  __shared__ uint16_t wbs[2][NT][136];  // W tile  [16][128] bf16

  // LoRA staging lives inside xa[0] (prologue-only lifetime)
  uint16_t* midb = &xa[0][0][0];        // [64][72] bf16 (4608 elems)
  uint16_t* lob = midb + 64 * 72;       // [16][72] bf16 (1152 elems)

  const int t = threadIdx.x;
  const int o0 = blockIdx.x * NT;
  const int wave = t >> 6;
  const int lane = t & 63;
  const int il = lane & 15;
  const int g = lane >> 4;
  const int m0 = wave * 16;

  // ---- prologue: stage midb (all threads) + lob (threads 0..63) ----
  {
    const int row = t >> 2;
    const int r0 = (t & 3) * 16;
    const float* mp = mid + row * R_ + r0;
    float4 a0 = *(const float4*)(mp);
    float4 a1 = *(const float4*)(mp + 4);
    float4 a2 = *(const float4*)(mp + 8);
    float4 a3 = *(const float4*)(mp + 12);
    uint4 p0, p1;
    p0.x = rne_pack(a0.x, a0.y); p0.y = rne_pack(a0.z, a0.w);
    p0.z = rne_pack(a1.x, a1.y); p0.w = rne_pack(a1.z, a1.w);
    p1.x = rne_pack(a2.x, a2.y); p1.y = rne_pack(a2.z, a2.w);
    p1.z = rne_pack(a3.x, a3.y); p1.w = rne_pack(a3.z, a3.w);
    *(uint4*)&midb[row * 72 + r0] = p0;
    *(uint4*)&midb[row * 72 + r0 + 8] = p1;
    if (t < 64) {
      const int row2 = t >> 2;
      const float* lp = lora_B + (size_t)(o0 + row2) * R_ + r0;
      float4 c0 = *(const float4*)(lp);
      float4 c1 = *(const float4*)(lp + 4);
      float4 c2 = *(const float4*)(lp + 8);
      float4 c3 = *(const float4*)(lp + 12);
      uint4 q0, q1;
      q0.x = rne_pack(c0.x, c0.y); q0.y = rne_pack(c0.z, c0.w);
      q0.z = rne_pack(c1.x, c1.y); q0.w = rne_pack(c1.z, c1.w);
      q1.x = rne_pack(c2.x, c2.y); q1.y = rne_pack(c2.z, c2.w);
      q1.z = rne_pack(c3.x, c3.y); q1.w = rne_pack(c3.z, c3.w);
      *(uint4*)&lob[row2 * 72 + r0] = q0;
      *(uint4*)&lob[row2 * 72 + r0 + 8] = q1;
    }
  }

  // ---- staging coordinates (fully coalesced) ----
  const int xrow = t >> 2, xs4 = t & 3;    // x: 64 rows x 4 lanes of 16B, x4 chunks
  const int wrow = t >> 4, ws16 = t & 15;  // W: 16 rows x 16 lanes of 16B, x2 chunks
  const uint16_t* xsrc = xbg + (size_t)xrow * K_;
  const int* wsrc = Wq + (size_t)(o0 + wrow) * K_;

  // 2-deep register banks (named scalars: all indices compile-time)
  uint4 rxa0, rxb0, rxc0, rxd0, rxa1, rxb1, rxc1, rxd1;
  int4 rwa0, rwb0, rwa1, rwb1;

#define LOADT(P, TT)                                        \
  do {                                                      \
    const int kt = (TT)*BK;                                 \
    rwa##P = *(const int4*)(wsrc + kt + ws16 * 4);          \
    rwb##P = *(const int4*)(wsrc + kt + 64 + ws16 * 4);     \
    rxa##P = *(const uint4*)(xsrc + kt + xs4 * 8);          \
    rxb##P = *(const uint4*)(xsrc + kt + 32 + xs4 * 8);     \
    rxc##P = *(const uint4*)(xsrc + kt + 64 + xs4 * 8);     \
    rxd##P = *(const uint4*)(xsrc + kt + 96 + xs4 * 8);     \
  } while (0)

#define STORE_LDS(P)                                        \
  do {                                                      \
    *(uint4*)&xa[P][xrow][xs4 * 8] = rxa##P;                \
    *(uint4*)&xa[P][xrow][32 + xs4 * 8] = rxb##P;           \
    *(uint4*)&xa[P][xrow][64 + xs4 * 8] = rxc##P;           \
    *(uint4*)&xa[P][xrow][96 + xs4 * 8] = rxd##P;           \
    uint2 wv0, wv1;                                         \
    wv0.x = wpack(rwa##P.x, rwa##P.y);                      \
    wv0.y = wpack(rwa##P.z, rwa##P.w);                      \
    wv1.x = wpack(rwb##P.x, rwb##P.y);                      \
    wv1.y = wpack(rwb##P.z, rwb##P.w);                      \
    *(uint2*)&wbs[P][wrow][ws16 * 4] = wv0;                 \
    *(uint2*)&wbs[P][wrow][64 + ws16 * 4] = wv1;            \
  } while (0)

#define MFMA_FROM(P)                                                          \
  do {                                                                        \
    _Pragma("unroll")                                                         \
    for (int kf = 0; kf < 4; ++kf) {                                          \
      s16x8 af = *(const s16x8*)&xa[P][m0 + il][kf * 32 + g * 8];             \
      s16x8 bf = *(const s16x8*)&wbs[P][il][kf * 32 + g * 8];                 \
      acc = __builtin_amdgcn_mfma_f32_16x16x32_bf16(af, bf, acc, 0, 0, 0);    \
    }                                                                         \
  } while (0)

  // fill the pipeline: tiles 0 and 1 in flight
  LOADT(0, 0);
  LOADT(1, 1);

  const float sc = scale[o0 + il];
  const float bi = bias[o0 + il];

  __syncthreads();  // midb/lob staged (also drains prologue loads)

  // ---- LoRA MFMAs: acc2 = mid[64x64] @ lora_B^T[64x16] ----
  f32x4 acc2 = {0.f, 0.f, 0.f, 0.f};
#pragma unroll
  for (int kf = 0; kf < 2; ++kf) {
    s16x8 am = *(const s16x8*)&midb[(m0 + il) * 72 + kf * 32 + g * 8];
    s16x8 bl = *(const s16x8*)&lob[il * 72 + kf * 32 + g * 8];
    acc2 = __builtin_amdgcn_mfma_f32_16x16x32_bf16(am, bl, acc2, 0, 0, 0);
  }
  __syncthreads();  // LoRA reads done before xa[0] is overwritten

  // ---- main K loop: 2-deep pipeline, one barrier per K-step ----
  f32x4 acc = {0.f, 0.f, 0.f, 0.f};
  for (int tt = 0; tt < NSTEP; tt += 2) {
    STORE_LDS(0);
    __syncthreads();
    if (tt + 2 < NSTEP) LOADT(0, tt + 2);
    MFMA_FROM(0);

    STORE_LDS(1);
    __syncthreads();
    if (tt + 3 < NSTEP) LOADT(1, tt + 3);
    MFMA_FROM(1);
  }
#undef LOADT
#undef STORE_LDS
#undef MFMA_FROM

  // ---- epilogue: C/D layout col=lane&15, row=(lane>>4)*4+reg ----
#pragma unroll
  for (int j = 0; j < 4; ++j) {
    const int b = m0 + g * 4 + j;
    out[(size_t)b * O_ + o0 + il] = sc * acc[j] + bi + 0.25f * acc2[j];
  }
}

// ---------------------------------------------------------------------------
extern "C" void kernel_launch(void* const* d_in, const int* in_sizes, int n_in,
                              void* d_out, int out_size, void* d_ws, size_t ws_size,
                              hipStream_t stream) {
  const float* x = (const float*)d_in[0];
  const int* Wq = (const int*)d_in[1];
  const float* scale = (const float*)d_in[2];
  const float* lora_A = (const float*)d_in[3];
  const float* lora_B = (const float*)d_in[4];
  const float* bias = (const float*)d_in[5];
  float* out = (float*)d_out;

  uint16_t* xbg = (uint16_t*)d_ws;                           // 1 MiB bf16 x
  float* mid = (float*)((char*)d_ws + (size_t)B_ * K_ * 2);  // 16 KiB fp32

  hipMemsetAsync(mid, 0, B_ * R_ * sizeof(float), stream);
  k_prep<<<256, 256, 0, stream>>>(x, lora_A, xbg, mid);
  k_main<<<O_ / NT, 256, 0, stream>>>(Wq, scale, lora_B, bias, xbg, mid, out);
}